// Round 1
// baseline (3679.983 us; speedup 1.0000x reference)
//
#include <hip/hip_runtime.h>
#include <hip/hip_bf16.h>
#include <stdint.h>

// Problem constants (fixed by setup_inputs)
#define IN_DIM   512
#define OUT_DIM  512
#define NSEG     65536
#define NROWS    409600
#define NIN      51200

typedef __attribute__((ext_vector_type(8))) short  short8v;   // 8 x bf16 (4 VGPRs)
typedef __attribute__((ext_vector_type(4))) float  float4v;   // MFMA C/D

static __device__ inline short f2bf(float f) {
    union { float f; unsigned int u; } c; c.f = f;
    unsigned int u = c.u;
    unsigned int r = (u + 0x7FFFu + ((u >> 16) & 1u)) >> 16;   // RNE
    return (short)(unsigned short)r;
}

// ---------------------------------------------------------------- zero agg
__global__ __launch_bounds__(256) void zero_f32(float4* p, int n4) {
    int i = blockIdx.x * 256 + threadIdx.x;
    int stride = gridDim.x * 256;
    for (; i < n4; i += stride) p[i] = make_float4(0.f, 0.f, 0.f, 0.f);
}

// ---------------------------------------------------------------- W -> bf16
__global__ __launch_bounds__(256) void cvt_w(const float4* __restrict__ src,
                                             short* __restrict__ dst, int n4) {
    int i = blockIdx.x * 256 + threadIdx.x;
    if (i < n4) {
        float4 v = src[i];
        union { short s[4]; uint64_t u; } p;
        p.s[0] = f2bf(v.x); p.s[1] = f2bf(v.y);
        p.s[2] = f2bf(v.z); p.s[3] = f2bf(v.w);
        *(uint64_t*)(dst + (size_t)i * 4) = p.u;
    }
}

// ---------------------------------------------------------------- scatter
// One 64-lane wave per row: lane covers 8 floats (2x float4), atomicAdd into
// the segment row. Wave's atomics cover a contiguous 2KiB region.
__global__ __launch_bounds__(256) void scatter_rows(const float* __restrict__ h,
                                                    const float* __restrict__ w,
                                                    const int*   __restrict__ idx,
                                                    float*       __restrict__ agg) {
    int row  = blockIdx.x * 4 + (threadIdx.x >> 6);
    int lane = threadIdx.x & 63;
    int seg  = idx[row];
    float wv = w[row % NIN];
    const float4* hrow = (const float4*)(h + (size_t)row * IN_DIM);
    float* dst = agg + (size_t)seg * IN_DIM;
#pragma unroll
    for (int j = 0; j < 2; ++j) {
        float4 v = hrow[lane + 64 * j];
        int base = (lane + 64 * j) * 4;
        atomicAdd(dst + base + 0, v.x * wv);
        atomicAdd(dst + base + 1, v.y * wv);
        atomicAdd(dst + base + 2, v.z * wv);
        atomicAdd(dst + base + 3, v.w * wv);
    }
}

// ---------------------------------------------------------------- GEMM
// out[65536,512] = agg @ W^T + b, bf16 MFMA 16x16x32.
// Block: 256 thr (4 waves, 2x2), tile 128x128, BK=64, LDS stride 72 (bank-balanced).
#define BM 128
#define BN 128
#define BK 64
#define LDSS 72

__global__ __launch_bounds__(256) void gemm_bf16(const float* __restrict__ agg,
                                                 const short* __restrict__ Wb,
                                                 const float* __restrict__ bias,
                                                 float* __restrict__ out) {
    __shared__ short As[BM * LDSS];
    __shared__ short Bs[BN * LDSS];

    const int t    = threadIdx.x;
    const int m0   = blockIdx.y * BM;
    const int n0   = blockIdx.x * BN;
    const int lane = t & 63;
    const int wv   = t >> 6;
    const int wm   = wv >> 1, wn = wv & 1;
    const int fm   = lane & 15;    // frag row/col within 16
    const int fq   = lane >> 4;    // quad 0..3

    float4v acc[4][4];
#pragma unroll
    for (int i = 0; i < 4; ++i)
#pragma unroll
        for (int j = 0; j < 4; ++j) acc[i][j] = (float4v){0.f, 0.f, 0.f, 0.f};

    for (int kt = 0; kt < IN_DIM; kt += BK) {
        __syncthreads();
        // Stage A (f32 -> bf16): 128 rows x 64 k = 1024 chunks of 8 elements
#pragma unroll
        for (int r = 0; r < 4; ++r) {
            int c = t + 256 * r;
            int row = c >> 3, cin = c & 7;
            const float4* src = (const float4*)(agg + (size_t)(m0 + row) * IN_DIM + kt + cin * 8);
            float4 v0 = src[0], v1 = src[1];
            short8v pk;
            pk[0] = f2bf(v0.x); pk[1] = f2bf(v0.y); pk[2] = f2bf(v0.z); pk[3] = f2bf(v0.w);
            pk[4] = f2bf(v1.x); pk[5] = f2bf(v1.y); pk[6] = f2bf(v1.z); pk[7] = f2bf(v1.w);
            *(short8v*)&As[row * LDSS + cin * 8] = pk;
        }
        // Stage B (already bf16)
#pragma unroll
        for (int r = 0; r < 4; ++r) {
            int c = t + 256 * r;
            int row = c >> 3, cin = c & 7;
            short8v v = *(const short8v*)(Wb + (size_t)(n0 + row) * IN_DIM + kt + cin * 8);
            *(short8v*)&Bs[row * LDSS + cin * 8] = v;
        }
        __syncthreads();
#pragma unroll
        for (int ks = 0; ks < 2; ++ks) {
            short8v a[4], b[4];
#pragma unroll
            for (int mt = 0; mt < 4; ++mt)
                a[mt] = *(const short8v*)&As[(wm * 64 + mt * 16 + fm) * LDSS + ks * 32 + fq * 8];
#pragma unroll
            for (int nt = 0; nt < 4; ++nt)
                b[nt] = *(const short8v*)&Bs[(wn * 64 + nt * 16 + fm) * LDSS + ks * 32 + fq * 8];
#pragma unroll
            for (int mt = 0; mt < 4; ++mt)
#pragma unroll
                for (int nt = 0; nt < 4; ++nt)
                    acc[mt][nt] = __builtin_amdgcn_mfma_f32_16x16x32_bf16(a[mt], b[nt], acc[mt][nt], 0, 0, 0);
        }
    }

    // Epilogue: C/D layout col = lane&15, row = quad*4 + reg
#pragma unroll
    for (int nt = 0; nt < 4; ++nt) {
        int col = n0 + wn * 64 + nt * 16 + fm;
        float bv = bias[col];
#pragma unroll
        for (int mt = 0; mt < 4; ++mt) {
            int rowb = m0 + wm * 64 + mt * 16 + fq * 4;
#pragma unroll
            for (int r = 0; r < 4; ++r)
                out[(size_t)(rowb + r) * OUT_DIM + col] = acc[mt][nt][r] + bv;
        }
    }
}

// ---------------------------------------------------------------- launch
extern "C" void kernel_launch(void* const* d_in, const int* in_sizes, int n_in,
                              void* d_out, int out_size, void* d_ws, size_t ws_size,
                              hipStream_t stream) {
    const float* h     = (const float*)d_in[0];
    const float* w     = (const float*)d_in[1];
    const float* lin_w = (const float*)d_in[2];
    const float* lin_b = (const float*)d_in[3];
    const int*   idx   = (const int*)d_in[4];

    float* agg = (float*)d_ws;                                             // 128 MiB
    short* Wb  = (short*)((char*)d_ws + (size_t)NSEG * IN_DIM * sizeof(float)); // 512 KiB
    float* out = (float*)d_out;

    zero_f32<<<8192, 256, 0, stream>>>((float4*)agg, NSEG * IN_DIM / 4);
    cvt_w<<<(OUT_DIM * IN_DIM / 4 + 255) / 256, 256, 0, stream>>>(
        (const float4*)lin_w, Wb, OUT_DIM * IN_DIM / 4);
    scatter_rows<<<NROWS / 4, 256, 0, stream>>>(h, w, idx, agg);
    dim3 grid(OUT_DIM / BN, NSEG / BM);
    gemm_bf16<<<grid, 256, 0, stream>>>(agg, Wb, lin_b, out);
}

// Round 2
// 1242.473 us; speedup vs baseline: 2.9618x; 2.9618x over previous
//
#include <hip/hip_runtime.h>
#include <hip/hip_bf16.h>
#include <stdint.h>

// Problem constants (fixed by setup_inputs)
#define IN_DIM   512
#define OUT_DIM  512
#define NSEG     65536
#define NROWS    409600
#define NIN      51200

typedef __attribute__((ext_vector_type(8))) short  short8v;   // 8 x bf16 (4 VGPRs)
typedef __attribute__((ext_vector_type(4))) float  float4v;   // MFMA C/D

static __device__ inline short f2bf(float f) {
    union { float f; unsigned int u; } c; c.f = f;
    unsigned int u = c.u;
    unsigned int r = (u + 0x7FFFu + ((u >> 16) & 1u)) >> 16;   // RNE
    return (short)(unsigned short)r;
}

// ---------------------------------------------------------------- zero counts
__global__ __launch_bounds__(256) void zero_counts(int* __restrict__ counts) {
    int i = blockIdx.x * 256 + threadIdx.x;
    if (i < NSEG) counts[i] = 0;
}

// ---------------------------------------------------------------- histogram
__global__ __launch_bounds__(256) void hist_kernel(const int* __restrict__ idx,
                                                   int* __restrict__ counts) {
    int i = blockIdx.x * 256 + threadIdx.x;
    if (i < NROWS) atomicAdd(&counts[idx[i]], 1);
}

// ---------------------------------------------------------------- scan
// Single block, 1024 threads, each owns 64 consecutive buckets.
// Produces exclusive offsets offs[0..NSEG] and initializes cursor = offs.
__global__ __launch_bounds__(1024) void scan_kernel(const int* __restrict__ counts,
                                                    int* __restrict__ offs,
                                                    int* __restrict__ cursor) {
    __shared__ int part[1024];
    const int t = threadIdx.x;
    const int base = t * 64;
    int local[64];
    int sum = 0;
#pragma unroll
    for (int k = 0; k < 64; ++k) { local[k] = counts[base + k]; sum += local[k]; }
    part[t] = sum;
    __syncthreads();
    // Hillis-Steele inclusive scan over 1024 partials
    for (int off = 1; off < 1024; off <<= 1) {
        int v = (t >= off) ? part[t - off] : 0;
        __syncthreads();
        part[t] += v;
        __syncthreads();
    }
    int running = part[t] - sum;   // exclusive prefix for this thread's chunk
#pragma unroll
    for (int k = 0; k < 64; ++k) {
        offs[base + k]   = running;
        cursor[base + k] = running;
        running += local[k];
    }
    if (t == 1023) offs[NSEG] = running;   // == NROWS
}

// ---------------------------------------------------------------- reorder
__global__ __launch_bounds__(256) void reorder_kernel(const int* __restrict__ idx,
                                                      int* __restrict__ cursor,
                                                      int* __restrict__ order) {
    int i = blockIdx.x * 256 + threadIdx.x;
    if (i < NROWS) {
        int pos = atomicAdd(&cursor[idx[i]], 1);
        order[pos] = i;
    }
}

// ---------------------------------------------------------------- gather-reduce
// One wave per segment: accumulate w[row%NIN]*h[row,:] over the segment's rows
// in f32 registers, store the 512-wide result row as bf16 (lane -> 8 contig).
__global__ __launch_bounds__(256) void gather_reduce(const float* __restrict__ h,
                                                     const float* __restrict__ w,
                                                     const int*   __restrict__ order,
                                                     const int*   __restrict__ offs,
                                                     short*       __restrict__ agg_bf) {
    int seg  = blockIdx.x * 4 + (threadIdx.x >> 6);
    int lane = threadIdx.x & 63;
    int start = offs[seg];
    int end   = offs[seg + 1];

    float4 a0 = make_float4(0.f, 0.f, 0.f, 0.f);
    float4 a1 = make_float4(0.f, 0.f, 0.f, 0.f);
    for (int j = start; j < end; ++j) {
        int row  = order[j];
        float wv = w[row % NIN];
        const float4* hr = (const float4*)(h + (size_t)row * IN_DIM);
        float4 v0 = hr[2 * lane];       // elements 8*lane .. 8*lane+3
        float4 v1 = hr[2 * lane + 1];   // elements 8*lane+4 .. 8*lane+7
        a0.x += v0.x * wv; a0.y += v0.y * wv; a0.z += v0.z * wv; a0.w += v0.w * wv;
        a1.x += v1.x * wv; a1.y += v1.y * wv; a1.z += v1.z * wv; a1.w += v1.w * wv;
    }
    short8v pk;
    pk[0] = f2bf(a0.x); pk[1] = f2bf(a0.y); pk[2] = f2bf(a0.z); pk[3] = f2bf(a0.w);
    pk[4] = f2bf(a1.x); pk[5] = f2bf(a1.y); pk[6] = f2bf(a1.z); pk[7] = f2bf(a1.w);
    *(short8v*)(agg_bf + (size_t)seg * IN_DIM + lane * 8) = pk;
}

// ---------------------------------------------------------------- W -> bf16
__global__ __launch_bounds__(256) void cvt_w(const float4* __restrict__ src,
                                             short* __restrict__ dst, int n4) {
    int i = blockIdx.x * 256 + threadIdx.x;
    if (i < n4) {
        float4 v = src[i];
        union { short s[4]; uint64_t u; } p;
        p.s[0] = f2bf(v.x); p.s[1] = f2bf(v.y);
        p.s[2] = f2bf(v.z); p.s[3] = f2bf(v.w);
        *(uint64_t*)(dst + (size_t)i * 4) = p.u;
    }
}

// ---------------------------------------------------------------- GEMM
// out[65536,512] = agg_bf @ Wb^T + b, bf16 MFMA 16x16x32.
// Block: 256 thr (4 waves, 2x2), tile 128x128, BK=64, LDS stride 72.
#define BM 128
#define BN 128
#define BK 64
#define LDSS 72

__global__ __launch_bounds__(256) void gemm_bf16(const short* __restrict__ Ab,
                                                 const short* __restrict__ Wb,
                                                 const float* __restrict__ bias,
                                                 float* __restrict__ out) {
    __shared__ short As[BM * LDSS];
    __shared__ short Bs[BN * LDSS];

    const int t    = threadIdx.x;
    const int m0   = blockIdx.y * BM;
    const int n0   = blockIdx.x * BN;
    const int lane = t & 63;
    const int wv   = t >> 6;
    const int wm   = wv >> 1, wn = wv & 1;
    const int fm   = lane & 15;    // frag row/col within 16
    const int fq   = lane >> 4;    // quad 0..3

    float4v acc[4][4];
#pragma unroll
    for (int i = 0; i < 4; ++i)
#pragma unroll
        for (int j = 0; j < 4; ++j) acc[i][j] = (float4v){0.f, 0.f, 0.f, 0.f};

    for (int kt = 0; kt < IN_DIM; kt += BK) {
        __syncthreads();
        // Stage A (bf16, plain copy): 128 rows x 64 k
#pragma unroll
        for (int r = 0; r < 4; ++r) {
            int c = t + 256 * r;
            int row = c >> 3, cin = c & 7;
            short8v v = *(const short8v*)(Ab + (size_t)(m0 + row) * IN_DIM + kt + cin * 8);
            *(short8v*)&As[row * LDSS + cin * 8] = v;
        }
        // Stage B (bf16)
#pragma unroll
        for (int r = 0; r < 4; ++r) {
            int c = t + 256 * r;
            int row = c >> 3, cin = c & 7;
            short8v v = *(const short8v*)(Wb + (size_t)(n0 + row) * IN_DIM + kt + cin * 8);
            *(short8v*)&Bs[row * LDSS + cin * 8] = v;
        }
        __syncthreads();
#pragma unroll
        for (int ks = 0; ks < 2; ++ks) {
            short8v a[4], b[4];
#pragma unroll
            for (int mt = 0; mt < 4; ++mt)
                a[mt] = *(const short8v*)&As[(wm * 64 + mt * 16 + fm) * LDSS + ks * 32 + fq * 8];
#pragma unroll
            for (int nt = 0; nt < 4; ++nt)
                b[nt] = *(const short8v*)&Bs[(wn * 64 + nt * 16 + fm) * LDSS + ks * 32 + fq * 8];
#pragma unroll
            for (int mt = 0; mt < 4; ++mt)
#pragma unroll
                for (int nt = 0; nt < 4; ++nt)
                    acc[mt][nt] = __builtin_amdgcn_mfma_f32_16x16x32_bf16(a[mt], b[nt], acc[mt][nt], 0, 0, 0);
        }
    }

    // Epilogue: C/D layout col = lane&15, row = quad*4 + reg
#pragma unroll
    for (int nt = 0; nt < 4; ++nt) {
        int col = n0 + wn * 64 + nt * 16 + fm;
        float bv = bias[col];
#pragma unroll
        for (int mt = 0; mt < 4; ++mt) {
            int rowb = m0 + wm * 64 + mt * 16 + fq * 4;
#pragma unroll
            for (int r = 0; r < 4; ++r)
                out[(size_t)(rowb + r) * OUT_DIM + col] = acc[mt][nt][r] + bv;
        }
    }
}

// ---------------------------------------------------------------- launch
extern "C" void kernel_launch(void* const* d_in, const int* in_sizes, int n_in,
                              void* d_out, int out_size, void* d_ws, size_t ws_size,
                              hipStream_t stream) {
    const float* h     = (const float*)d_in[0];
    const float* w     = (const float*)d_in[1];
    const float* lin_w = (const float*)d_in[2];
    const float* lin_b = (const float*)d_in[3];
    const int*   idx   = (const int*)d_in[4];

    // Workspace layout (all offsets 256-aligned):
    char* ws = (char*)d_ws;
    short* agg_bf = (short*)ws;                                   // 64 MiB
    size_t off = (size_t)NSEG * IN_DIM * sizeof(short);
    short* Wb = (short*)(ws + off);      off += (size_t)OUT_DIM * IN_DIM * sizeof(short); // 512 KiB
    int* counts = (int*)(ws + off);      off += (size_t)NSEG * sizeof(int);
    int* offs   = (int*)(ws + off);      off += (size_t)(NSEG + 64) * sizeof(int);
    int* cursor = (int*)(ws + off);      off += (size_t)NSEG * sizeof(int);
    int* order  = (int*)(ws + off);      off += (size_t)NROWS * sizeof(int);
    float* out = (float*)d_out;

    zero_counts<<<NSEG / 256, 256, 0, stream>>>(counts);
    hist_kernel<<<NROWS / 256, 256, 0, stream>>>(idx, counts);
    scan_kernel<<<1, 1024, 0, stream>>>(counts, offs, cursor);
    reorder_kernel<<<NROWS / 256, 256, 0, stream>>>(idx, cursor, order);
    gather_reduce<<<NSEG / 4, 256, 0, stream>>>(h, w, order, offs, agg_bf);
    cvt_w<<<(OUT_DIM * IN_DIM / 4 + 255) / 256, 256, 0, stream>>>(
        (const float4*)lin_w, Wb, OUT_DIM * IN_DIM / 4);
    dim3 grid(OUT_DIM / BN, NSEG / BM);
    gemm_bf16<<<grid, 256, 0, stream>>>(agg_bf, Wb, lin_b, out);
}